// Round 1
// baseline (5999.936 us; speedup 1.0000x reference)
//
#include <hip/hip_runtime.h>

// Coattention: B=32, Lq=Ld=1024, H=1024, fp32.
//   A  = q @ d^T                       [B, L, L]
//   P_d[q,dd] = softmax over dd (mask dd>=d_len)   (== ad^T)
//   P_q[q,dd] = softmax over q  (mask q>=q_len)    (== aq)
//   out2 sq^T = P_d   @ d      [B, L, H]
//   out3 sd^T = P_q^T @ q      [B, L, H]
//   out1 cd^T = P_q^T @ sq^T   [B, L, H]
// P is never materialized: GEMMs normalize A on the fly from per-row stats.

constexpr int BATCH = 32;
constexpr int L  = 1024;  // Lq == Ld
constexpr int HD = 1024;

constexpr int BM = 64, BN = 64, BK = 16;

// ---------------- Kernel 1: A[b,qi,di] = sum_h q[b,qi,h] * d[b,di,h] ----------------
__global__ __launch_bounds__(256) void affinity_kernel(
    const float* __restrict__ q, const float* __restrict__ d,
    float* __restrict__ A) {
  __shared__ float As[BK][BM + 1];
  __shared__ float Bs[BK][BN + 1];
  const int b  = blockIdx.z;
  const int m0 = blockIdx.y * BM;
  const int n0 = blockIdx.x * BN;
  const int tid = threadIdx.x;
  const int tx = tid % 16, ty = tid / 16;
  const float* qb = q + (size_t)b * L * HD;
  const float* db = d + (size_t)b * L * HD;
  float acc[4][4] = {};
  const int lrow = tid / 4;        // 0..63
  const int lk   = (tid % 4) * 4;  // 0,4,8,12
  for (int k0 = 0; k0 < HD; k0 += BK) {
    const float4 av = *(const float4*)(qb + (size_t)(m0 + lrow) * HD + k0 + lk);
    const float4 bv = *(const float4*)(db + (size_t)(n0 + lrow) * HD + k0 + lk);
    As[lk + 0][lrow] = av.x; As[lk + 1][lrow] = av.y;
    As[lk + 2][lrow] = av.z; As[lk + 3][lrow] = av.w;
    Bs[lk + 0][lrow] = bv.x; Bs[lk + 1][lrow] = bv.y;
    Bs[lk + 2][lrow] = bv.z; Bs[lk + 3][lrow] = bv.w;
    __syncthreads();
#pragma unroll
    for (int k = 0; k < BK; ++k) {
      float a[4], bb[4];
#pragma unroll
      for (int i = 0; i < 4; ++i) a[i] = As[k][ty * 4 + i];
#pragma unroll
      for (int j = 0; j < 4; ++j) bb[j] = Bs[k][tx * 4 + j];
#pragma unroll
      for (int i = 0; i < 4; ++i)
#pragma unroll
        for (int j = 0; j < 4; ++j) acc[i][j] += a[i] * bb[j];
    }
    __syncthreads();
  }
  float* Ab = A + (size_t)b * L * L;
#pragma unroll
  for (int i = 0; i < 4; ++i) {
    const int row = m0 + ty * 4 + i;
#pragma unroll
    for (int j = 0; j < 4; ++j)
      Ab[(size_t)row * L + n0 + tx * 4 + j] = acc[i][j];
  }
}

// ------- Kernel 2: per-(b,q) max/sumexp over dd < d_len[b] (one wave per row) -------
__global__ __launch_bounds__(256) void row_stats_kernel(
    const float* __restrict__ A, const int* __restrict__ d_len,
    float* __restrict__ m_out, float* __restrict__ s_out) {
  const int wave = threadIdx.x / 64, lane = threadIdx.x % 64;
  const int row = blockIdx.x * 4 + wave;  // in [0, BATCH*L)
  const int b = row / L;
  const int len = d_len[b];
  const float* base = A + (size_t)row * L;
  float m = -1e30f;
  for (int k = lane; k < len; k += 64) m = fmaxf(m, base[k]);
#pragma unroll
  for (int off = 32; off > 0; off >>= 1) m = fmaxf(m, __shfl_xor(m, off, 64));
  float s = 0.f;
  for (int k = lane; k < len; k += 64) s += __expf(base[k] - m);
#pragma unroll
  for (int off = 32; off > 0; off >>= 1) s += __shfl_xor(s, off, 64);
  if (lane == 0) { m_out[row] = m; s_out[row] = s; }
}

// ------- Kernel 3: per-(b,dd) max/sumexp over q < q_len[b] (one thread per col) -------
__global__ __launch_bounds__(256) void col_stats_kernel(
    const float* __restrict__ A, const int* __restrict__ q_len,
    float* __restrict__ m_out, float* __restrict__ s_out) {
  const int col = blockIdx.x * 256 + threadIdx.x;  // in [0, BATCH*L)
  const int b = col / L, di = col % L;
  const int len = q_len[b];
  const float* base = A + (size_t)b * L * L + di;
  float m = -1e30f, s = 0.f;
  for (int k = 0; k < len; ++k) {
    const float v = base[(size_t)k * L];
    const float mn = fmaxf(m, v);
    s = s * __expf(m - mn) + __expf(v - mn);
    m = mn;
  }
  m_out[col] = m;
  s_out[col] = s;
}

// ------- Kernel 4: C[row,h] = (1/s[row]) * sum_k mask(k) * exp(Asrc[row,k]-m[row]) * B[k,h]
//   TRANSA=false: Asrc[row,k] = A[b][row*L + k]   (rows are q, k is dd)
//   TRANSA=true : Asrc[row,k] = A[b][k*L + row]   (rows are dd, k is q)
template <bool TRANSA>
__global__ __launch_bounds__(256) void norm_gemm_kernel(
    const float* __restrict__ A, const float* __restrict__ m_arr,
    const float* __restrict__ s_arr, const int* __restrict__ len_arr,
    const float* __restrict__ Bmat, float* __restrict__ C) {
  __shared__ float Ps[BK][BM + 1];
  __shared__ float Bs[BK][BN + 1];
  const int b  = blockIdx.z;
  const int m0 = blockIdx.y * BM;  // output-row tile
  const int n0 = blockIdx.x * BN;  // h tile
  const int tid = threadIdx.x;
  const int tx = tid % 16, ty = tid / 16;
  const int len = len_arr[b];
  const float* Ab = A + (size_t)b * L * L;
  const float* Bb = Bmat + (size_t)b * L * HD;
  float acc[4][4] = {};
  for (int k0 = 0; k0 < L; k0 += BK) {
    if (TRANSA) {
      const int kb = tid / 64;  // 0..3
      const int r  = tid % 64;
      const float mm = m_arr[(size_t)b * L + m0 + r];
#pragma unroll
      for (int i = 0; i < 4; ++i) {
        const int kk = kb + i * 4;
        const int kg = k0 + kk;
        const float v = Ab[(size_t)kg * L + m0 + r];
        Ps[kk][r] = (kg < len) ? __expf(v - mm) : 0.f;
      }
    } else {
      const int r  = tid / 4;
      const int kk = (tid % 4) * 4;
      const float4 v = *(const float4*)(Ab + (size_t)(m0 + r) * L + k0 + kk);
      const float mm = m_arr[(size_t)b * L + m0 + r];
      Ps[kk + 0][r] = (k0 + kk + 0 < len) ? __expf(v.x - mm) : 0.f;
      Ps[kk + 1][r] = (k0 + kk + 1 < len) ? __expf(v.y - mm) : 0.f;
      Ps[kk + 2][r] = (k0 + kk + 2 < len) ? __expf(v.z - mm) : 0.f;
      Ps[kk + 3][r] = (k0 + kk + 3 < len) ? __expf(v.w - mm) : 0.f;
    }
#pragma unroll
    for (int i = 0; i < 4; ++i) {
      const int e = tid + i * 256;
      const int h = e % 64, k = e / 64;
      Bs[k][h] = Bb[(size_t)(k0 + k) * HD + n0 + h];
    }
    __syncthreads();
#pragma unroll
    for (int k = 0; k < BK; ++k) {
      float a[4], bb[4];
#pragma unroll
      for (int i = 0; i < 4; ++i) a[i] = Ps[k][ty * 4 + i];
#pragma unroll
      for (int j = 0; j < 4; ++j) bb[j] = Bs[k][tx * 4 + j];
#pragma unroll
      for (int i = 0; i < 4; ++i)
#pragma unroll
        for (int j = 0; j < 4; ++j) acc[i][j] += a[i] * bb[j];
    }
    __syncthreads();
  }
#pragma unroll
  for (int i = 0; i < 4; ++i) {
    const int row = m0 + ty * 4 + i;
    const float inv = 1.f / s_arr[(size_t)b * L + row];
#pragma unroll
    for (int j = 0; j < 4; ++j)
      C[(size_t)b * L * HD + (size_t)row * HD + n0 + tx * 4 + j] =
          acc[i][j] * inv;
  }
}

extern "C" void kernel_launch(void* const* d_in, const int* in_sizes, int n_in,
                              void* d_out, int out_size, void* d_ws, size_t ws_size,
                              hipStream_t stream) {
  const float* q     = (const float*)d_in[0];
  const float* d     = (const float*)d_in[1];
  const int*   q_len = (const int*)d_in[2];
  const int*   d_len = (const int*)d_in[3];
  float* out = (float*)d_out;

  // workspace layout: A (B*L*L fp32), then 4 stats vectors (B*L fp32 each)
  float* A   = (float*)d_ws;
  const size_t aElems = (size_t)BATCH * L * L;
  float* m_d = A + aElems;
  float* s_d = m_d + (size_t)BATCH * L;
  float* m_q = s_d + (size_t)BATCH * L;
  float* s_q = m_q + (size_t)BATCH * L;

  dim3 gA(L / BN, L / BM, BATCH);
  affinity_kernel<<<gA, 256, 0, stream>>>(q, d, A);

  row_stats_kernel<<<dim3(BATCH * L / 4), 256, 0, stream>>>(A, d_len, m_d, s_d);
  col_stats_kernel<<<dim3(BATCH * L / 256), 256, 0, stream>>>(A, q_len, m_q, s_q);

  float* cdT = out;                              // [B, L, HD]
  float* sqT = out + (size_t)BATCH * L * HD;     // [B, L, HD]
  float* sdT = sqT + (size_t)BATCH * L * HD;     // [B, L, HD]

  dim3 gN(HD / BN, L / BM, BATCH);
  // out2: sq^T = P_d @ d        (rows=q, k=dd, mask d_len)
  norm_gemm_kernel<false><<<gN, 256, 0, stream>>>(A, m_d, s_d, d_len, d, sqT);
  // out3: sd^T = P_q^T @ q      (rows=dd, k=q, mask q_len)
  norm_gemm_kernel<true><<<gN, 256, 0, stream>>>(A, m_q, s_q, q_len, q, sdT);
  // out1: cd^T = P_q^T @ sq^T   (same P, B = sq^T just written)
  norm_gemm_kernel<true><<<gN, 256, 0, stream>>>(A, m_q, s_q, q_len, sqT, cdT);
}